// Round 6
// baseline (228.529 us; speedup 1.0000x reference)
//
#include <hip/hip_runtime.h>
#include <hip/hip_bf16.h>

#define D 128
#define NPB 64
#define EPB1 2048          // edges per block in pass-1 kernels
#define SCAN1_IT 80        // max items/thread in scan1 (supports n1 <= 81920)

typedef __attribute__((ext_vector_type(8))) short short8;   // 8 bf16 (4 VGPRs)
typedef __attribute__((ext_vector_type(4))) float f32x4;

static __device__ __forceinline__ unsigned short f32_to_bf16(float f) {
    unsigned int u = __float_as_uint(f);
    u = (u + 0x7FFFu + ((u >> 16) & 1u)) >> 16;   // RNE
    return (unsigned short)u;
}
static __device__ __forceinline__ float bf16lo(unsigned int r) {
    return __uint_as_float(r << 16);
}
static __device__ __forceinline__ float bf16hi(unsigned int r) {
    return __uint_as_float(r & 0xFFFF0000u);
}

// ---------------------------------------------------------------------------
// K0: convert w_embed rows into MFMA B-fragment layout (bf16), two sets:
//     set0 = rows 0..127 (src proj), set1 = rows 130..257 (dst proj).
// ---------------------------------------------------------------------------
__global__ void __launch_bounds__(256)
wconv_kernel(const float* __restrict__ w_embed, unsigned short* __restrict__ w_frag)
{
    int t = blockIdx.x * 256 + threadIdx.x;     // 4096 lane-frags total
    if (t >= 4096) return;
    int set  = t >> 11;
    int ks   = (t >> 9) & 3;
    int nt   = (t >> 6) & 7;
    int lane = t & 63;
    int wrow0 = set ? 130 : 0;
    int col   = nt * 16 + (lane & 15);
    int kbase = ks * 32 + (lane >> 4) * 8;
    unsigned short* dst = w_frag + (size_t)t * 8;
#pragma unroll
    for (int j = 0; j < 8; ++j)
        dst[j] = f32_to_bf16(w_embed[(size_t)(wrow0 + kbase + j) * D + col]);
}

// ---------------------------------------------------------------------------
// K1: MFMA node projection.  proj[n] = bf16(feats[n] @ W), att[n] = feats[n].w_att
// ---------------------------------------------------------------------------
__global__ void __launch_bounds__(256)
proj_mfma_kernel(const float* __restrict__ feats,          // [n,128] f32
                 const unsigned short* __restrict__ wfrag, // this matrix's frag set
                 const float* __restrict__ w_att, int wrow, int n_nodes,
                 unsigned short* __restrict__ proj,        // [n,128] bf16
                 float* __restrict__ att)                  // [n] f32
{
    __shared__ unsigned short s_tile[NPB * D];   // 16 KB, swizzled
    __shared__ float s_red[NPB][4];

    const int tid = threadIdx.x;
    const int node0 = blockIdx.x * NPB;

#pragma unroll
    for (int it = 0; it < 8; ++it) {
        int idx = it * 256 + tid;          // 2048 float4 groups
        int row = idx >> 5, c4 = idx & 31;
        int n = node0 + row;
        float4 v = (n < n_nodes)
                 ? *reinterpret_cast<const float4*>(&feats[(size_t)n * D + c4 * 4])
                 : make_float4(0.f, 0.f, 0.f, 0.f);
        unsigned short h[4];
        h[0] = f32_to_bf16(v.x); h[1] = f32_to_bf16(v.y);
        h[2] = f32_to_bf16(v.z); h[3] = f32_to_bf16(v.w);
        int byte = row * 256 + c4 * 8;
        byte ^= (row & 7) << 4;
        *reinterpret_cast<ushort4*>((char*)s_tile + byte) = *reinterpret_cast<ushort4*>(h);
    }
    __syncthreads();

    const int wv = tid >> 6, lane = tid & 63;

    f32x4 acc[8];
#pragma unroll
    for (int i = 0; i < 8; ++i) acc[i] = {0.f, 0.f, 0.f, 0.f};

    const int arow = wv * 16 + (lane & 15);
#pragma unroll
    for (int ks = 0; ks < 4; ++ks) {
        int abyte = arow * 256 + ks * 64 + (lane >> 4) * 16;
        abyte ^= (arow & 7) << 4;
        short8 a = *reinterpret_cast<const short8*>((char*)s_tile + abyte);
#pragma unroll
        for (int nt = 0; nt < 8; ++nt) {
            short8 b = *reinterpret_cast<const short8*>(wfrag + ((size_t)(ks * 8 + nt) * 64 + lane) * 8);
            acc[nt] = __builtin_amdgcn_mfma_f32_16x16x32_bf16(a, b, acc[nt], 0, 0, 0);
        }
    }

    // C/D: col = lane&15, row = (lane>>4)*4 + r
#pragma unroll
    for (int nt = 0; nt < 8; ++nt) {
#pragma unroll
        for (int r = 0; r < 4; ++r) {
            int node = node0 + wv * 16 + (lane >> 4) * 4 + r;
            if (node < n_nodes)
                proj[(size_t)node * D + nt * 16 + (lane & 15)] = f32_to_bf16(acc[nt][r]);
        }
    }

    // att scalar: 256 threads = 64 nodes x 4 k-quarters (reads swizzled LDS)
    const int na = tid & 63, kq = tid >> 6;
    float p = 0.f;
#pragma unroll
    for (int k = kq * 32; k < kq * 32 + 32; ++k) {
        int byte = (na * 256 + k * 2) ^ ((na & 7) << 4);
        unsigned short h = *reinterpret_cast<const unsigned short*>((char*)s_tile + byte);
        p += __uint_as_float(((unsigned int)h) << 16) * w_att[wrow + k];
    }
    s_red[na][kq] = p;
    __syncthreads();
    if (tid < NPB) {
        int n = node0 + tid;
        if (n < n_nodes)
            att[n] = s_red[tid][0] + s_red[tid][1] + s_red[tid][2] + s_red[tid][3];
    }
}

// ---------------------------------------------------------------------------
// K_h1: per-block coarse histogram (dst>>8), LDS-binned, no contended atomics.
//     block_bins layout is BIN-MAJOR: bb[bin*nblk1 + blk].
// ---------------------------------------------------------------------------
__global__ void __launch_bounds__(256)
hist1_kernel(const int* __restrict__ edst, int* __restrict__ bb,
             int n_edge, int nblk1, int nb1)
{
    __shared__ int bins[256];
    const int tid = threadIdx.x, blk = blockIdx.x;
    bins[tid] = 0;
    __syncthreads();
#pragma unroll
    for (int it = 0; it < EPB1 / 256; ++it) {
        int e = blk * EPB1 + it * 256 + tid;
        if (e < n_edge) atomicAdd(&bins[((unsigned)edst[e]) >> 8], 1);
    }
    __syncthreads();
    if (tid < nb1) bb[tid * nblk1 + blk] = bins[tid];
}

// ---------------------------------------------------------------------------
// K_scan1: single-block exclusive scan (in-place) over n1 = nb1*nblk1 values;
//     also emits binstart[b] = scanned value at index b*nblk1, binstart[nb1]=n_edge.
// ---------------------------------------------------------------------------
__global__ void __launch_bounds__(1024)
scan1_kernel(int* __restrict__ bb, int* __restrict__ binstart,
             int n1, int nblk1, int nb1, int n_edge)
{
    __shared__ int s_w[16];
    const int tid = threadIdx.x;
    const int lane = tid & 63, wid = tid >> 6;
    const int base = tid * SCAN1_IT;

    int v[SCAN1_IT];
    int tsum = 0;
#pragma unroll
    for (int i = 0; i < SCAN1_IT; ++i) {
        int idx = base + i;
        v[i] = (idx < n1) ? bb[idx] : 0;
        tsum += v[i];
    }
    int x = tsum;
#pragma unroll
    for (int off = 1; off < 64; off <<= 1) {
        int y = __shfl_up(x, off);
        if (lane >= off) x += y;
    }
    if (lane == 63) s_w[wid] = x;
    __syncthreads();
    if (tid < 16) {
        int w = s_w[tid];
#pragma unroll
        for (int off = 1; off < 16; off <<= 1) {
            int y = __shfl_up(w, off);
            if (tid >= off) w += y;
        }
        s_w[tid] = w - s_w[tid];   // exclusive wave offset... careful: w inclusive
    }
    __syncthreads();
    // s_w[wid] currently holds (inclusive scan of wave sums) - (own wave sum) = exclusive
    int run = s_w[wid] + (x - tsum);
#pragma unroll
    for (int i = 0; i < SCAN1_IT; ++i) {
        int idx = base + i;
        if (idx < n1) {
            bb[idx] = run;
            if (idx % nblk1 == 0) binstart[idx / nblk1] = run;
            run += v[i];
        }
    }
    if (tid == 0) binstart[nb1] = n_edge;
}

// ---------------------------------------------------------------------------
// K_p1: score+exp per edge, rank via LDS cursor (coarse bin), write meta1
//     into coarse-bucket order.  meta1 = {src | (dlow<<24), ew, d0, d1}.
// ---------------------------------------------------------------------------
__global__ void __launch_bounds__(256)
pass1_kernel(const int* __restrict__ esrc, const int* __restrict__ edst,
             const float* __restrict__ dist,
             const float* __restrict__ src_att, const float* __restrict__ dst_att,
             const float* __restrict__ w_att,
             const int* __restrict__ bb,       // scanned (bin,blk) start positions
             float4* __restrict__ meta1, int n_edge, int nblk1, int nb1)
{
    __shared__ int cur[256];
    const int tid = threadIdx.x, blk = blockIdx.x;
    if (tid < nb1) cur[tid] = bb[tid * nblk1 + blk];
    __syncthreads();

    const float wa0 = w_att[128], wa1 = w_att[129];
#pragma unroll
    for (int it = 0; it < EPB1 / 256; ++it) {
        int e = blk * EPB1 + it * 256 + tid;
        if (e < n_edge) {
            int s = esrc[e];
            int d = edst[e];
            float2 dd = *reinterpret_cast<const float2*>(&dist[2 * (size_t)e]);
            float sc = src_att[s] + dst_att[d] + dd.x * wa0 + dd.y * wa1;
            sc = (sc >= 0.f) ? sc : 0.2f * sc;
            float ew = __expf(sc);
            int pos = atomicAdd(&cur[((unsigned)d) >> 8], 1);
            meta1[pos] = make_float4(__int_as_float(s | ((d & 255) << 24)), ew, dd.x, dd.y);
        }
    }
}

// ---------------------------------------------------------------------------
// K_p2: one block per coarse bucket.  Builds fine histogram + per-dst sums
//     (LDS atomics), 256-wide LDS scan -> writes offsets[] and sums[],
//     then scatters meta2 = {src, ew} into exact CSR order.
// ---------------------------------------------------------------------------
__global__ void __launch_bounds__(1024)
pass2_kernel(const float4* __restrict__ meta1, const int* __restrict__ binstart,
             int* __restrict__ offsets,
             float* __restrict__ sw_g, float* __restrict__ s0_g, float* __restrict__ s1_g,
             float2* __restrict__ meta2, int n_dst)
{
    __shared__ int   s_cnt[256];
    __shared__ int   s_cur[256];
    __shared__ float s_sw[256], s_s0[256], s_s1[256];

    const int tid = threadIdx.x, b = blockIdx.x;
    const int bstart = binstart[b];
    const int bend   = binstart[b + 1];
    const int bsize  = bend - bstart;

    if (tid < 256) { s_cnt[tid] = 0; s_sw[tid] = 0.f; s_s0[tid] = 0.f; s_s1[tid] = 0.f; }
    __syncthreads();

    for (int i = tid; i < bsize; i += 1024) {
        float4 m = meta1[bstart + i];
        int bits = __float_as_int(m.x);
        int dlow = ((unsigned)bits) >> 24;
        atomicAdd(&s_cnt[dlow], 1);
        atomicAdd(&s_sw[dlow], m.y);
        atomicAdd(&s_s0[dlow], m.y * m.z);
        atomicAdd(&s_s1[dlow], m.y * m.w);
    }
    __syncthreads();

    int orig = 0;
    if (tid < 256) orig = s_cnt[tid];
    // inclusive Hillis-Steele scan over 256 (in-place, barriers outside cond)
#pragma unroll
    for (int off = 1; off < 256; off <<= 1) {
        int v2 = 0;
        if (tid < 256 && tid >= off) v2 = s_cnt[tid - off];
        __syncthreads();
        if (tid < 256) s_cnt[tid] += v2;
        __syncthreads();
    }
    if (tid < 256) {
        int excl = s_cnt[tid] - orig;
        int gidx = b * 256 + tid;
        s_cur[tid] = bstart + excl;
        if (gidx < n_dst) {
            offsets[gidx] = bstart + excl;
            sw_g[gidx] = s_sw[tid];
            s0_g[gidx] = s_s0[tid];
            s1_g[gidx] = s_s1[tid];
        } else if (gidx == n_dst) {
            offsets[gidx] = bstart + excl;   // == n_edge for the last real slot
        }
    }
    __syncthreads();

    for (int i = tid; i < bsize; i += 1024) {
        float4 m = meta1[bstart + i];
        int bits = __float_as_int(m.x);
        int dlow = ((unsigned)bits) >> 24;
        int src  = bits & 0xFFFFFF;
        int pos = atomicAdd(&s_cur[dlow], 1);
        meta2[pos] = make_float2(__int_as_float(src), m.y);
    }
}

// ---------------------------------------------------------------------------
// K5: wave-per-dst aggregation; 8-wide unrolled gather pipeline.
// ---------------------------------------------------------------------------
__global__ void __launch_bounds__(256)
aggregate_kernel(const int* __restrict__ offsets, const float2* __restrict__ meta,
                 const unsigned short* __restrict__ srcp,   // bf16 [n_src,128]
                 const unsigned short* __restrict__ dstp,   // bf16 [n_dst,128]
                 const float* __restrict__ sw_g, const float* __restrict__ s0_g,
                 const float* __restrict__ s1_g,
                 const float* __restrict__ w_embed,
                 float* __restrict__ out, int n_dst)
{
    const int wv = threadIdx.x >> 6;
    const int lane = threadIdx.x & 63;
    const int d = blockIdx.x * 4 + wv;
    if (d >= n_dst) return;

    const int c0 = 2 * lane;
    float2* op = reinterpret_cast<float2*>(&out[(size_t)d * D + c0]);

    int begin = __builtin_amdgcn_readfirstlane(offsets[d]);
    int end   = __builtin_amdgcn_readfirstlane(offsets[d + 1]);
    if (begin == end) { *op = make_float2(0.f, 0.f); return; }

    float acc0 = 0.f, acc1 = 0.f;

#define EDGE_ACC(m)                                                                   \
    {                                                                                 \
        unsigned int r = *reinterpret_cast<const unsigned int*>(                      \
            &srcp[(size_t)__float_as_int((m).x) * D + c0]);                           \
        acc0 += (m).y * bf16lo(r);                                                    \
        acc1 += (m).y * bf16hi(r);                                                    \
    }

    int i = begin;
    for (; i + 8 <= end; i += 8) {
        float2 m0 = meta[i + 0];
        float2 m1 = meta[i + 1];
        float2 m2 = meta[i + 2];
        float2 m3 = meta[i + 3];
        float2 m4 = meta[i + 4];
        float2 m5 = meta[i + 5];
        float2 m6 = meta[i + 6];
        float2 m7 = meta[i + 7];
        EDGE_ACC(m0) EDGE_ACC(m1) EDGE_ACC(m2) EDGE_ACC(m3)
        EDGE_ACC(m4) EDGE_ACC(m5) EDGE_ACC(m6) EDGE_ACC(m7)
    }
    for (; i + 4 <= end; i += 4) {
        float2 m0 = meta[i + 0];
        float2 m1 = meta[i + 1];
        float2 m2 = meta[i + 2];
        float2 m3 = meta[i + 3];
        EDGE_ACC(m0) EDGE_ACC(m1) EDGE_ACC(m2) EDGE_ACC(m3)
    }
    for (; i < end; ++i) {
        float2 m0 = meta[i];
        EDGE_ACC(m0)
    }
#undef EDGE_ACC

    const float inv  = 1.f / sw_g[d];
    const float swd0 = s0_g[d], swd1 = s1_g[d];
    const float2 wd0 = *reinterpret_cast<const float2*>(&w_embed[128 * D + c0]);
    const float2 wd1 = *reinterpret_cast<const float2*>(&w_embed[129 * D + c0]);
    unsigned int rd = *reinterpret_cast<const unsigned int*>(&dstp[(size_t)d * D + c0]);

    float o0 = (acc0 + swd0 * wd0.x + swd1 * wd1.x) * inv + bf16lo(rd);
    float o1 = (acc1 + swd0 * wd0.y + swd1 * wd1.y) * inv + bf16hi(rd);
    *op = make_float2(fmaxf(o0, 0.f), fmaxf(o1, 0.f));
}

// ---------------------------------------------------------------------------
extern "C" void kernel_launch(void* const* d_in, const int* in_sizes, int n_in,
                              void* d_out, int out_size, void* d_ws, size_t ws_size,
                              hipStream_t stream)
{
    const float* src_feat = (const float*)d_in[0];   // [N_SRC,128]
    const int*   esrc     = (const int*)d_in[1];     // [E]
    const float* dst_feat = (const float*)d_in[2];   // [N_DST,128]
    const int*   edst     = (const int*)d_in[3];     // [E]
    const float* dist     = (const float*)d_in[4];   // [E,2]
    const float* w_att    = (const float*)d_in[5];   // [258]
    const float* w_embed  = (const float*)d_in[6];   // [258,128]

    const int n_src  = in_sizes[0] / D;
    const int n_edge = in_sizes[1];
    const int n_dst  = in_sizes[2] / D;

    const int nb1   = (n_dst + 255) / 256;           // coarse buckets (196)
    const int nblk1 = (n_edge + EPB1 - 1) / EPB1;    // pass-1 blocks (391)
    const int n1    = nb1 * nblk1;                   // 76636 <= 81920 ok

    // ---- workspace carve-up (256B-aligned) ----
    char* p = (char*)d_ws;
    auto carve = [&p](size_t bytes) {
        char* r = p;
        p += (bytes + 255) & ~size_t(255);
        return r;
    };
    unsigned short* src_projb = (unsigned short*)carve((size_t)n_src * D * 2);  // bf16
    unsigned short* dst_projb = (unsigned short*)carve((size_t)n_dst * D * 2);  // bf16
    float* src_att   = (float*)carve((size_t)n_src * 4);
    float* dst_att   = (float*)carve((size_t)n_dst * 4);
    int*   offsets   = (int*)carve((size_t)(n_dst + 1) * 4);
    float* sw_g      = (float*)carve((size_t)n_dst * 4);
    float* s0_g      = (float*)carve((size_t)n_dst * 4);
    float* s1_g      = (float*)carve((size_t)n_dst * 4);
    int*   bb        = (int*)carve((size_t)n1 * 4);
    int*   binstart  = (int*)carve((size_t)(nb1 + 1) * 4);
    unsigned short* w_frag = (unsigned short*)carve(2 * 4 * 8 * 64 * 8 * 2);  // 64 KB
    float4* meta1    = (float4*)carve((size_t)n_edge * 16);
    float2* meta2    = (float2*)carve((size_t)n_edge * 8);
    (void)ws_size;

    // K0: W -> bf16 fragment layout
    wconv_kernel<<<16, 256, 0, stream>>>(w_embed, w_frag);

    // K1: MFMA node projections (both bf16 out)
    proj_mfma_kernel<<<(n_src + NPB - 1) / NPB, 256, 0, stream>>>(
        src_feat, w_frag, w_att, 0, n_src, src_projb, src_att);
    proj_mfma_kernel<<<(n_dst + NPB - 1) / NPB, 256, 0, stream>>>(
        dst_feat, w_frag + 16384, w_att, 130, n_dst, dst_projb, dst_att);

    // K_h1: coarse per-block histogram (LDS-binned)
    hist1_kernel<<<nblk1, 256, 0, stream>>>(edst, bb, n_edge, nblk1, nb1);

    // K_scan1: scan (bin,blk) counts -> start positions + binstart
    scan1_kernel<<<1, 1024, 0, stream>>>(bb, binstart, n1, nblk1, nb1, n_edge);

    // K_p1: score/exp + coarse-bucket scatter (LDS cursors only)
    pass1_kernel<<<nblk1, 256, 0, stream>>>(esrc, edst, dist, src_att, dst_att,
                                            w_att, bb, meta1, n_edge, nblk1, nb1);

    // K_p2: fine sort within buckets + offsets + per-dst sums
    pass2_kernel<<<nb1, 1024, 0, stream>>>(meta1, binstart, offsets,
                                           sw_g, s0_g, s1_g, meta2, n_dst);

    // K5: aggregation
    aggregate_kernel<<<(n_dst + 3) / 4, 256, 0, stream>>>(
        offsets, meta2, src_projb, dst_projb, sw_g, s0_g, s1_g, w_embed,
        (float*)d_out, n_dst);
}

// Round 7
// 121.795 us; speedup vs baseline: 1.8763x; 1.8763x over previous
//
#include <hip/hip_runtime.h>
#include <hip/hip_bf16.h>

#define D 128
#define NPB 64
#define EPB1 2048          // edges per block in pass-1 kernels
#define SCAN_T 256
#define SCAN_IT 8
#define SCAN_TILE (SCAN_T * SCAN_IT)   // 2048

typedef __attribute__((ext_vector_type(8))) short short8;   // 8 bf16 (4 VGPRs)
typedef __attribute__((ext_vector_type(4))) float f32x4;

static __device__ __forceinline__ unsigned short f32_to_bf16(float f) {
    unsigned int u = __float_as_uint(f);
    u = (u + 0x7FFFu + ((u >> 16) & 1u)) >> 16;   // RNE
    return (unsigned short)u;
}
static __device__ __forceinline__ float bf16lo(unsigned int r) {
    return __uint_as_float(r << 16);
}
static __device__ __forceinline__ float bf16hi(unsigned int r) {
    return __uint_as_float(r & 0xFFFF0000u);
}

// ---------------------------------------------------------------------------
// K0: convert w_embed rows into MFMA B-fragment layout (bf16), two sets:
//     set0 = rows 0..127 (src proj), set1 = rows 130..257 (dst proj).
// ---------------------------------------------------------------------------
__global__ void __launch_bounds__(256)
wconv_kernel(const float* __restrict__ w_embed, unsigned short* __restrict__ w_frag)
{
    int t = blockIdx.x * 256 + threadIdx.x;     // 4096 lane-frags total
    if (t >= 4096) return;
    int set  = t >> 11;
    int ks   = (t >> 9) & 3;
    int nt   = (t >> 6) & 7;
    int lane = t & 63;
    int wrow0 = set ? 130 : 0;
    int col   = nt * 16 + (lane & 15);
    int kbase = ks * 32 + (lane >> 4) * 8;
    unsigned short* dst = w_frag + (size_t)t * 8;
#pragma unroll
    for (int j = 0; j < 8; ++j)
        dst[j] = f32_to_bf16(w_embed[(size_t)(wrow0 + kbase + j) * D + col]);
}

// ---------------------------------------------------------------------------
// K1: MFMA node projection.  proj[n] = bf16(feats[n] @ W), att[n] = feats[n].w_att
// ---------------------------------------------------------------------------
__global__ void __launch_bounds__(256)
proj_mfma_kernel(const float* __restrict__ feats,          // [n,128] f32
                 const unsigned short* __restrict__ wfrag, // this matrix's frag set
                 const float* __restrict__ w_att, int wrow, int n_nodes,
                 unsigned short* __restrict__ proj,        // [n,128] bf16
                 float* __restrict__ att)                  // [n] f32
{
    __shared__ unsigned short s_tile[NPB * D];   // 16 KB, swizzled
    __shared__ float s_red[NPB][4];

    const int tid = threadIdx.x;
    const int node0 = blockIdx.x * NPB;

#pragma unroll
    for (int it = 0; it < 8; ++it) {
        int idx = it * 256 + tid;          // 2048 float4 groups
        int row = idx >> 5, c4 = idx & 31;
        int n = node0 + row;
        float4 v = (n < n_nodes)
                 ? *reinterpret_cast<const float4*>(&feats[(size_t)n * D + c4 * 4])
                 : make_float4(0.f, 0.f, 0.f, 0.f);
        unsigned short h[4];
        h[0] = f32_to_bf16(v.x); h[1] = f32_to_bf16(v.y);
        h[2] = f32_to_bf16(v.z); h[3] = f32_to_bf16(v.w);
        int byte = row * 256 + c4 * 8;
        byte ^= (row & 7) << 4;
        *reinterpret_cast<ushort4*>((char*)s_tile + byte) = *reinterpret_cast<ushort4*>(h);
    }
    __syncthreads();

    const int wv = tid >> 6, lane = tid & 63;

    f32x4 acc[8];
#pragma unroll
    for (int i = 0; i < 8; ++i) acc[i] = {0.f, 0.f, 0.f, 0.f};

    const int arow = wv * 16 + (lane & 15);
#pragma unroll
    for (int ks = 0; ks < 4; ++ks) {
        int abyte = arow * 256 + ks * 64 + (lane >> 4) * 16;
        abyte ^= (arow & 7) << 4;
        short8 a = *reinterpret_cast<const short8*>((char*)s_tile + abyte);
#pragma unroll
        for (int nt = 0; nt < 8; ++nt) {
            short8 b = *reinterpret_cast<const short8*>(wfrag + ((size_t)(ks * 8 + nt) * 64 + lane) * 8);
            acc[nt] = __builtin_amdgcn_mfma_f32_16x16x32_bf16(a, b, acc[nt], 0, 0, 0);
        }
    }

    // C/D: col = lane&15, row = (lane>>4)*4 + r
#pragma unroll
    for (int nt = 0; nt < 8; ++nt) {
#pragma unroll
        for (int r = 0; r < 4; ++r) {
            int node = node0 + wv * 16 + (lane >> 4) * 4 + r;
            if (node < n_nodes)
                proj[(size_t)node * D + nt * 16 + (lane & 15)] = f32_to_bf16(acc[nt][r]);
        }
    }

    // att scalar: 256 threads = 64 nodes x 4 k-quarters (reads swizzled LDS)
    const int na = tid & 63, kq = tid >> 6;
    float p = 0.f;
#pragma unroll
    for (int k = kq * 32; k < kq * 32 + 32; ++k) {
        int byte = (na * 256 + k * 2) ^ ((na & 7) << 4);
        unsigned short h = *reinterpret_cast<const unsigned short*>((char*)s_tile + byte);
        p += __uint_as_float(((unsigned int)h) << 16) * w_att[wrow + k];
    }
    s_red[na][kq] = p;
    __syncthreads();
    if (tid < NPB) {
        int n = node0 + tid;
        if (n < n_nodes)
            att[n] = s_red[tid][0] + s_red[tid][1] + s_red[tid][2] + s_red[tid][3];
    }
}

// ---------------------------------------------------------------------------
// K_h1: per-block coarse histogram (dst>>8), LDS-binned.
//     block_bins layout is BIN-MAJOR: bb[bin*nblk1 + blk].
// ---------------------------------------------------------------------------
__global__ void __launch_bounds__(256)
hist1_kernel(const int* __restrict__ edst, int* __restrict__ bb,
             int n_edge, int nblk1, int nb1)
{
    __shared__ int bins[256];
    const int tid = threadIdx.x, blk = blockIdx.x;
    bins[tid] = 0;
    __syncthreads();
#pragma unroll
    for (int it = 0; it < EPB1 / 256; ++it) {
        int e = blk * EPB1 + it * 256 + tid;
        if (e < n_edge) atomicAdd(&bins[((unsigned)edst[e]) >> 8], 1);
    }
    __syncthreads();
    if (tid < nb1) bb[tid * nblk1 + blk] = bins[tid];
}

// ---------------------------------------------------------------------------
// K_sA/sB/sC: multi-block exclusive scan of bb (n1 values), in place.
//     Fixup also emits binstart[b] = bb[b*nblk1], binstart[nb1] = n_edge.
// ---------------------------------------------------------------------------
__global__ void __launch_bounds__(SCAN_T)
scanA_block_kernel(const int* __restrict__ in, int* __restrict__ out,
                   int* __restrict__ blocksum, int n)
{
    __shared__ int s_w[4];
    const int blk = blockIdx.x, tid = threadIdx.x;
    const int lane = tid & 63, wid = tid >> 6;
    const int base = blk * SCAN_TILE + tid * SCAN_IT;

    int v[SCAN_IT];
    int tsum = 0;
#pragma unroll
    for (int i = 0; i < SCAN_IT; ++i) {
        v[i] = (base + i < n) ? in[base + i] : 0;
        tsum += v[i];
    }
    int x = tsum;
#pragma unroll
    for (int off = 1; off < 64; off <<= 1) {
        int y = __shfl_up(x, off);
        if (lane >= off) x += y;
    }
    if (lane == 63) s_w[wid] = x;
    __syncthreads();
    if (tid == 0) {
        int a = 0;
#pragma unroll
        for (int w = 0; w < 4; ++w) { int t = s_w[w]; s_w[w] = a; a += t; }
        blocksum[blk] = a;
    }
    __syncthreads();
    int run = s_w[wid] + (x - tsum);
#pragma unroll
    for (int i = 0; i < SCAN_IT; ++i) {
        if (base + i < n) out[base + i] = run;
        run += v[i];
    }
}

__global__ void __launch_bounds__(64)
scanA_sums_kernel(int* __restrict__ blocksum, int nblk)
{
    const int tid = threadIdx.x;
    int v = (tid < nblk) ? blocksum[tid] : 0;
    int x = v;
#pragma unroll
    for (int off = 1; off < 64; off <<= 1) {
        int y = __shfl_up(x, off);
        if (tid >= off) x += y;
    }
    if (tid < nblk) blocksum[tid] = x - v;   // exclusive
}

__global__ void scanA_fixup_kernel(int* __restrict__ bb, const int* __restrict__ blocksum,
                                   int* __restrict__ binstart,
                                   int n1, int nblk1, int nb1, int n_edge)
{
    int i = blockIdx.x * blockDim.x + threadIdx.x;
    if (i < n1) {
        int o = bb[i] + blocksum[i / SCAN_TILE];
        bb[i] = o;
        if (i % nblk1 == 0) binstart[i / nblk1] = o;
    }
    if (i == 0) binstart[nb1] = n_edge;
}

// ---------------------------------------------------------------------------
// K_p1: score+exp per edge, rank via LDS cursor (coarse bin), write meta1
//     into coarse-bucket order.  meta1 = {src | (dlow<<24), ew, d0, d1}.
// ---------------------------------------------------------------------------
__global__ void __launch_bounds__(256)
pass1_kernel(const int* __restrict__ esrc, const int* __restrict__ edst,
             const float* __restrict__ dist,
             const float* __restrict__ src_att, const float* __restrict__ dst_att,
             const float* __restrict__ w_att,
             const int* __restrict__ bb,       // scanned (bin,blk) start positions
             float4* __restrict__ meta1, int n_edge, int nblk1, int nb1)
{
    __shared__ int cur[256];
    const int tid = threadIdx.x, blk = blockIdx.x;
    if (tid < nb1) cur[tid] = bb[tid * nblk1 + blk];
    __syncthreads();

    const float wa0 = w_att[128], wa1 = w_att[129];
#pragma unroll
    for (int it = 0; it < EPB1 / 256; ++it) {
        int e = blk * EPB1 + it * 256 + tid;
        if (e < n_edge) {
            int s = esrc[e];
            int d = edst[e];
            float2 dd = *reinterpret_cast<const float2*>(&dist[2 * (size_t)e]);
            float sc = src_att[s] + dst_att[d] + dd.x * wa0 + dd.y * wa1;
            sc = (sc >= 0.f) ? sc : 0.2f * sc;
            float ew = __expf(sc);
            int pos = atomicAdd(&cur[((unsigned)d) >> 8], 1);
            meta1[pos] = make_float4(__int_as_float(s | ((d & 255) << 24)), ew, dd.x, dd.y);
        }
    }
}

// ---------------------------------------------------------------------------
// K_p2: one block per coarse bucket.  Builds fine histogram + per-dst sums
//     (LDS atomics), 256-wide LDS scan -> writes offsets[] and sums[],
//     then scatters meta2 = {src, ew} into exact CSR order.
// ---------------------------------------------------------------------------
__global__ void __launch_bounds__(1024)
pass2_kernel(const float4* __restrict__ meta1, const int* __restrict__ binstart,
             int* __restrict__ offsets,
             float* __restrict__ sw_g, float* __restrict__ s0_g, float* __restrict__ s1_g,
             float2* __restrict__ meta2, int n_dst)
{
    __shared__ int   s_cnt[256];
    __shared__ int   s_cur[256];
    __shared__ float s_sw[256], s_s0[256], s_s1[256];

    const int tid = threadIdx.x, b = blockIdx.x;
    const int bstart = binstart[b];
    const int bend   = binstart[b + 1];
    const int bsize  = bend - bstart;

    if (tid < 256) { s_cnt[tid] = 0; s_sw[tid] = 0.f; s_s0[tid] = 0.f; s_s1[tid] = 0.f; }
    __syncthreads();

    for (int i = tid; i < bsize; i += 1024) {
        float4 m = meta1[bstart + i];
        int bits = __float_as_int(m.x);
        int dlow = ((unsigned)bits) >> 24;
        atomicAdd(&s_cnt[dlow], 1);
        atomicAdd(&s_sw[dlow], m.y);
        atomicAdd(&s_s0[dlow], m.y * m.z);
        atomicAdd(&s_s1[dlow], m.y * m.w);
    }
    __syncthreads();

    int orig = 0;
    if (tid < 256) orig = s_cnt[tid];
    // inclusive Hillis-Steele scan over 256 (in-place, barriers outside cond)
#pragma unroll
    for (int off = 1; off < 256; off <<= 1) {
        int v2 = 0;
        if (tid < 256 && tid >= off) v2 = s_cnt[tid - off];
        __syncthreads();
        if (tid < 256) s_cnt[tid] += v2;
        __syncthreads();
    }
    if (tid < 256) {
        int excl = s_cnt[tid] - orig;
        int gidx = b * 256 + tid;
        s_cur[tid] = bstart + excl;
        if (gidx < n_dst) {
            offsets[gidx] = bstart + excl;
            sw_g[gidx] = s_sw[tid];
            s0_g[gidx] = s_s0[tid];
            s1_g[gidx] = s_s1[tid];
        } else if (gidx == n_dst) {
            offsets[gidx] = bstart + excl;
        }
    }
    __syncthreads();

    for (int i = tid; i < bsize; i += 1024) {
        float4 m = meta1[bstart + i];
        int bits = __float_as_int(m.x);
        int dlow = ((unsigned)bits) >> 24;
        int src  = bits & 0xFFFFFF;
        int pos = atomicAdd(&s_cur[dlow], 1);
        meta2[pos] = make_float2(__int_as_float(src), m.y);
    }
}

// ---------------------------------------------------------------------------
// K5: wave-per-dst aggregation; 8-wide unrolled gather pipeline.
// ---------------------------------------------------------------------------
__global__ void __launch_bounds__(256)
aggregate_kernel(const int* __restrict__ offsets, const float2* __restrict__ meta,
                 const unsigned short* __restrict__ srcp,   // bf16 [n_src,128]
                 const unsigned short* __restrict__ dstp,   // bf16 [n_dst,128]
                 const float* __restrict__ sw_g, const float* __restrict__ s0_g,
                 const float* __restrict__ s1_g,
                 const float* __restrict__ w_embed,
                 float* __restrict__ out, int n_dst)
{
    const int wv = threadIdx.x >> 6;
    const int lane = threadIdx.x & 63;
    const int d = blockIdx.x * 4 + wv;
    if (d >= n_dst) return;

    const int c0 = 2 * lane;
    float2* op = reinterpret_cast<float2*>(&out[(size_t)d * D + c0]);

    int begin = __builtin_amdgcn_readfirstlane(offsets[d]);
    int end   = __builtin_amdgcn_readfirstlane(offsets[d + 1]);
    if (begin == end) { *op = make_float2(0.f, 0.f); return; }

    float acc0 = 0.f, acc1 = 0.f;

#define EDGE_ACC(m)                                                                   \
    {                                                                                 \
        unsigned int r = *reinterpret_cast<const unsigned int*>(                      \
            &srcp[(size_t)__float_as_int((m).x) * D + c0]);                           \
        acc0 += (m).y * bf16lo(r);                                                    \
        acc1 += (m).y * bf16hi(r);                                                    \
    }

    int i = begin;
    for (; i + 8 <= end; i += 8) {
        float2 m0 = meta[i + 0];
        float2 m1 = meta[i + 1];
        float2 m2 = meta[i + 2];
        float2 m3 = meta[i + 3];
        float2 m4 = meta[i + 4];
        float2 m5 = meta[i + 5];
        float2 m6 = meta[i + 6];
        float2 m7 = meta[i + 7];
        EDGE_ACC(m0) EDGE_ACC(m1) EDGE_ACC(m2) EDGE_ACC(m3)
        EDGE_ACC(m4) EDGE_ACC(m5) EDGE_ACC(m6) EDGE_ACC(m7)
    }
    for (; i + 4 <= end; i += 4) {
        float2 m0 = meta[i + 0];
        float2 m1 = meta[i + 1];
        float2 m2 = meta[i + 2];
        float2 m3 = meta[i + 3];
        EDGE_ACC(m0) EDGE_ACC(m1) EDGE_ACC(m2) EDGE_ACC(m3)
    }
    for (; i < end; ++i) {
        float2 m0 = meta[i];
        EDGE_ACC(m0)
    }
#undef EDGE_ACC

    const float inv  = 1.f / sw_g[d];
    const float swd0 = s0_g[d], swd1 = s1_g[d];
    const float2 wd0 = *reinterpret_cast<const float2*>(&w_embed[128 * D + c0]);
    const float2 wd1 = *reinterpret_cast<const float2*>(&w_embed[129 * D + c0]);
    unsigned int rd = *reinterpret_cast<const unsigned int*>(&dstp[(size_t)d * D + c0]);

    float o0 = (acc0 + swd0 * wd0.x + swd1 * wd1.x) * inv + bf16lo(rd);
    float o1 = (acc1 + swd0 * wd0.y + swd1 * wd1.y) * inv + bf16hi(rd);
    *op = make_float2(fmaxf(o0, 0.f), fmaxf(o1, 0.f));
}

// ---------------------------------------------------------------------------
extern "C" void kernel_launch(void* const* d_in, const int* in_sizes, int n_in,
                              void* d_out, int out_size, void* d_ws, size_t ws_size,
                              hipStream_t stream)
{
    const float* src_feat = (const float*)d_in[0];   // [N_SRC,128]
    const int*   esrc     = (const int*)d_in[1];     // [E]
    const float* dst_feat = (const float*)d_in[2];   // [N_DST,128]
    const int*   edst     = (const int*)d_in[3];     // [E]
    const float* dist     = (const float*)d_in[4];   // [E,2]
    const float* w_att    = (const float*)d_in[5];   // [258]
    const float* w_embed  = (const float*)d_in[6];   // [258,128]

    const int n_src  = in_sizes[0] / D;
    const int n_edge = in_sizes[1];
    const int n_dst  = in_sizes[2] / D;

    const int nb1   = (n_dst + 255) / 256;           // coarse buckets (196)
    const int nblk1 = (n_edge + EPB1 - 1) / EPB1;    // pass-1 blocks (391)
    const int n1    = nb1 * nblk1;                   // 76636

    // ---- workspace carve-up (256B-aligned) ----
    char* p = (char*)d_ws;
    auto carve = [&p](size_t bytes) {
        char* r = p;
        p += (bytes + 255) & ~size_t(255);
        return r;
    };
    unsigned short* src_projb = (unsigned short*)carve((size_t)n_src * D * 2);  // bf16
    unsigned short* dst_projb = (unsigned short*)carve((size_t)n_dst * D * 2);  // bf16
    float* src_att   = (float*)carve((size_t)n_src * 4);
    float* dst_att   = (float*)carve((size_t)n_dst * 4);
    int*   offsets   = (int*)carve((size_t)(n_dst + 1) * 4);
    float* sw_g      = (float*)carve((size_t)n_dst * 4);
    float* s0_g      = (float*)carve((size_t)n_dst * 4);
    float* s1_g      = (float*)carve((size_t)n_dst * 4);
    int*   bb        = (int*)carve((size_t)n1 * 4);
    int*   binstart  = (int*)carve((size_t)(nb1 + 1) * 4);
    int*   blocksum  = (int*)carve(64 * 4);
    unsigned short* w_frag = (unsigned short*)carve(2 * 4 * 8 * 64 * 8 * 2);  // 64 KB
    float4* meta1    = (float4*)carve((size_t)n_edge * 16);
    float2* meta2    = (float2*)carve((size_t)n_edge * 8);
    (void)ws_size;

    // K0: W -> bf16 fragment layout
    wconv_kernel<<<16, 256, 0, stream>>>(w_embed, w_frag);

    // K1: MFMA node projections (both bf16 out)
    proj_mfma_kernel<<<(n_src + NPB - 1) / NPB, 256, 0, stream>>>(
        src_feat, w_frag, w_att, 0, n_src, src_projb, src_att);
    proj_mfma_kernel<<<(n_dst + NPB - 1) / NPB, 256, 0, stream>>>(
        dst_feat, w_frag + 16384, w_att, 130, n_dst, dst_projb, dst_att);

    // K_h1: coarse per-block histogram (LDS-binned)
    hist1_kernel<<<nblk1, 256, 0, stream>>>(edst, bb, n_edge, nblk1, nb1);

    // K_sA/sB/sC: multi-block exclusive scan of bb -> start positions + binstart
    const int nblkS = (n1 + SCAN_TILE - 1) / SCAN_TILE;   // 38 <= 64
    scanA_block_kernel<<<nblkS, SCAN_T, 0, stream>>>(bb, bb, blocksum, n1);
    scanA_sums_kernel<<<1, 64, 0, stream>>>(blocksum, nblkS);
    scanA_fixup_kernel<<<(n1 + 255) / 256, 256, 0, stream>>>(bb, blocksum, binstart,
                                                             n1, nblk1, nb1, n_edge);

    // K_p1: score/exp + coarse-bucket scatter (LDS cursors only)
    pass1_kernel<<<nblk1, 256, 0, stream>>>(esrc, edst, dist, src_att, dst_att,
                                            w_att, bb, meta1, n_edge, nblk1, nb1);

    // K_p2: fine sort within buckets + offsets + per-dst sums
    pass2_kernel<<<nb1, 1024, 0, stream>>>(meta1, binstart, offsets,
                                           sw_g, s0_g, s1_g, meta2, n_dst);

    // K5: aggregation
    aggregate_kernel<<<(n_dst + 3) / 4, 256, 0, stream>>>(
        offsets, meta2, src_projb, dst_projb, sw_g, s0_g, s1_g, w_embed,
        (float*)d_out, n_dst);
}

// Round 8
// 117.349 us; speedup vs baseline: 1.9474x; 1.0379x over previous
//
#include <hip/hip_runtime.h>
#include <hip/hip_bf16.h>

#define D 128
#define NPB 64
#define EPB1 2048          // edges per pass1/hist1 block
#define BDST 64            // dsts per fine bucket (bucket = dst >> 6)
#define CAP 2048           // max edges per bucket on the fast path (avg ~1023)
#define MAXBINS 1024       // LDS cursor capacity (nb1 = ceil(n_dst/64) = 782)

typedef __attribute__((ext_vector_type(8))) short short8;   // 8 bf16 (4 VGPRs)
typedef __attribute__((ext_vector_type(4))) float f32x4;

static __device__ __forceinline__ unsigned short f32_to_bf16(float f) {
    unsigned int u = __float_as_uint(f);
    u = (u + 0x7FFFu + ((u >> 16) & 1u)) >> 16;   // RNE
    return (unsigned short)u;
}
static __device__ __forceinline__ float bf16lo(unsigned int r) {
    return __uint_as_float(r << 16);
}
static __device__ __forceinline__ float bf16hi(unsigned int r) {
    return __uint_as_float(r & 0xFFFF0000u);
}

// ---------------------------------------------------------------------------
// K0: convert w_embed rows into MFMA B-fragment layout (bf16), two sets:
//     set0 = rows 0..127 (src proj), set1 = rows 130..257 (dst proj).
// ---------------------------------------------------------------------------
__global__ void __launch_bounds__(256)
wconv_kernel(const float* __restrict__ w_embed, unsigned short* __restrict__ w_frag)
{
    int t = blockIdx.x * 256 + threadIdx.x;     // 4096 lane-frags total
    if (t >= 4096) return;
    int set  = t >> 11;
    int ks   = (t >> 9) & 3;
    int nt   = (t >> 6) & 7;
    int lane = t & 63;
    int wrow0 = set ? 130 : 0;
    int col   = nt * 16 + (lane & 15);
    int kbase = ks * 32 + (lane >> 4) * 8;
    unsigned short* dst = w_frag + (size_t)t * 8;
#pragma unroll
    for (int j = 0; j < 8; ++j)
        dst[j] = f32_to_bf16(w_embed[(size_t)(wrow0 + kbase + j) * D + col]);
}

// ---------------------------------------------------------------------------
// K1: fused MFMA node projection (src blocks then dst blocks in one grid).
//     proj[n] = bf16(feats[n] @ W), att[n] = feats[n].w_att
// ---------------------------------------------------------------------------
__global__ void __launch_bounds__(256)
proj_both_kernel(const float* __restrict__ src_feat, const float* __restrict__ dst_feat,
                 const unsigned short* __restrict__ wfrag_base,
                 const float* __restrict__ w_att,
                 int n_src, int n_dst, int nblk_src,
                 unsigned short* __restrict__ srcp, unsigned short* __restrict__ dstp,
                 float* __restrict__ src_att, float* __restrict__ dst_att)
{
    const bool is_src = (blockIdx.x < nblk_src);
    const float* feats = is_src ? src_feat : dst_feat;
    const unsigned short* wfrag = is_src ? wfrag_base : wfrag_base + 16384;
    const int wrow = is_src ? 0 : 130;
    const int n_nodes = is_src ? n_src : n_dst;
    unsigned short* proj = is_src ? srcp : dstp;
    float* att = is_src ? src_att : dst_att;
    const int blk = is_src ? blockIdx.x : blockIdx.x - nblk_src;

    __shared__ unsigned short s_tile[NPB * D];   // 16 KB, swizzled
    __shared__ float s_red[NPB][4];

    const int tid = threadIdx.x;
    const int node0 = blk * NPB;

#pragma unroll
    for (int it = 0; it < 8; ++it) {
        int idx = it * 256 + tid;          // 2048 float4 groups
        int row = idx >> 5, c4 = idx & 31;
        int n = node0 + row;
        float4 v = (n < n_nodes)
                 ? *reinterpret_cast<const float4*>(&feats[(size_t)n * D + c4 * 4])
                 : make_float4(0.f, 0.f, 0.f, 0.f);
        unsigned short h[4];
        h[0] = f32_to_bf16(v.x); h[1] = f32_to_bf16(v.y);
        h[2] = f32_to_bf16(v.z); h[3] = f32_to_bf16(v.w);
        int byte = row * 256 + c4 * 8;
        byte ^= (row & 7) << 4;
        *reinterpret_cast<ushort4*>((char*)s_tile + byte) = *reinterpret_cast<ushort4*>(h);
    }
    __syncthreads();

    const int wv = tid >> 6, lane = tid & 63;

    f32x4 acc[8];
#pragma unroll
    for (int i = 0; i < 8; ++i) acc[i] = {0.f, 0.f, 0.f, 0.f};

    const int arow = wv * 16 + (lane & 15);
#pragma unroll
    for (int ks = 0; ks < 4; ++ks) {
        int abyte = arow * 256 + ks * 64 + (lane >> 4) * 16;
        abyte ^= (arow & 7) << 4;
        short8 a = *reinterpret_cast<const short8*>((char*)s_tile + abyte);
#pragma unroll
        for (int nt = 0; nt < 8; ++nt) {
            short8 b = *reinterpret_cast<const short8*>(wfrag + ((size_t)(ks * 8 + nt) * 64 + lane) * 8);
            acc[nt] = __builtin_amdgcn_mfma_f32_16x16x32_bf16(a, b, acc[nt], 0, 0, 0);
        }
    }

    // C/D: col = lane&15, row = (lane>>4)*4 + r
#pragma unroll
    for (int nt = 0; nt < 8; ++nt) {
#pragma unroll
        for (int r = 0; r < 4; ++r) {
            int node = node0 + wv * 16 + (lane >> 4) * 4 + r;
            if (node < n_nodes)
                proj[(size_t)node * D + nt * 16 + (lane & 15)] = f32_to_bf16(acc[nt][r]);
        }
    }

    // att scalar: 256 threads = 64 nodes x 4 k-quarters (reads swizzled LDS)
    const int na = tid & 63, kq = tid >> 6;
    float p = 0.f;
#pragma unroll
    for (int k = kq * 32; k < kq * 32 + 32; ++k) {
        int byte = (na * 256 + k * 2) ^ ((na & 7) << 4);
        unsigned short h = *reinterpret_cast<const unsigned short*>((char*)s_tile + byte);
        p += __uint_as_float(((unsigned int)h) << 16) * w_att[wrow + k];
    }
    s_red[na][kq] = p;
    __syncthreads();
    if (tid < NPB) {
        int n = node0 + tid;
        if (n < n_nodes)
            att[n] = s_red[tid][0] + s_red[tid][1] + s_red[tid][2] + s_red[tid][3];
    }
}

// ---------------------------------------------------------------------------
// K_h1: per-block bucket histogram (dst>>6), LDS-binned.
//     bb layout BIN-MAJOR: bb[bin*nblk1 + blk].
// ---------------------------------------------------------------------------
__global__ void __launch_bounds__(256)
hist1_kernel(const int* __restrict__ edst, int* __restrict__ bb,
             int n_edge, int nblk1, int nb1)
{
    __shared__ int bins[MAXBINS];
    const int tid = threadIdx.x, blk = blockIdx.x;
    for (int i = tid; i < nb1; i += 256) bins[i] = 0;
    __syncthreads();
#pragma unroll
    for (int it = 0; it < EPB1 / 256; ++it) {
        int e = blk * EPB1 + it * 256 + tid;
        if (e < n_edge) atomicAdd(&bins[((unsigned)edst[e]) >> 6], 1);
    }
    __syncthreads();
    for (int i = tid; i < nb1; i += 256) bb[(size_t)i * nblk1 + blk] = bins[i];
}

// ---------------------------------------------------------------------------
// K_s1: per-bin exclusive scan along blocks (one wave per bin), in place.
//     Emits bintot[bin].
// ---------------------------------------------------------------------------
__global__ void __launch_bounds__(64)
scan_perbin_kernel(int* __restrict__ bb, int* __restrict__ bintot, int nblk1)
{
    const int bin = blockIdx.x, lane = threadIdx.x;
    const size_t base = (size_t)bin * nblk1;
    int carry = 0;
    for (int s = 0; s < nblk1; s += 64) {
        int idx = s + lane;
        int v = (idx < nblk1) ? bb[base + idx] : 0;
        int x = v;
#pragma unroll
        for (int off = 1; off < 64; off <<= 1) {
            int y = __shfl_up(x, off);
            if (lane >= off) x += y;
        }
        if (idx < nblk1) bb[base + idx] = carry + x - v;
        carry += __shfl(x, 63);
    }
    if (lane == 0) bintot[bin] = carry;
}

// ---------------------------------------------------------------------------
// K_s2: exclusive scan of bintot[nb1] -> binstart[nb1+1]  (single block)
// ---------------------------------------------------------------------------
__global__ void __launch_bounds__(1024)
scan_bins_kernel(const int* __restrict__ bintot, int* __restrict__ binstart,
                 int nb1, int n_edge)
{
    __shared__ int s_w[16];
    const int tid = threadIdx.x;
    const int lane = tid & 63, wid = tid >> 6;
    int v = (tid < nb1) ? bintot[tid] : 0;
    int x = v;
#pragma unroll
    for (int off = 1; off < 64; off <<= 1) {
        int y = __shfl_up(x, off);
        if (lane >= off) x += y;
    }
    if (lane == 63) s_w[wid] = x;
    __syncthreads();
    if (tid < 16) {
        int w = s_w[tid];
#pragma unroll
        for (int off = 1; off < 16; off <<= 1) {
            int y = __shfl_up(w, off);
            if (tid >= off) w += y;
        }
        s_w[tid] = w - s_w[tid];   // exclusive wave offset
    }
    __syncthreads();
    if (tid < nb1) binstart[tid] = s_w[wid] + (x - v);
    if (tid == 0) binstart[nb1] = n_edge;
}

// ---------------------------------------------------------------------------
// K_p1: score+exp per edge, rank via LDS cursor (bucket), write meta1
//     into bucket order.  meta1 = {src | (dlow<<24), ew, d0, d1}, dlow = d&63.
// ---------------------------------------------------------------------------
__global__ void __launch_bounds__(256)
pass1_kernel(const int* __restrict__ esrc, const int* __restrict__ edst,
             const float* __restrict__ dist,
             const float* __restrict__ src_att, const float* __restrict__ dst_att,
             const float* __restrict__ w_att,
             const int* __restrict__ bb, const int* __restrict__ binstart,
             float4* __restrict__ meta1, int n_edge, int nblk1, int nb1)
{
    __shared__ int cur[MAXBINS];
    const int tid = threadIdx.x, blk = blockIdx.x;
    for (int i = tid; i < nb1; i += 256)
        cur[i] = binstart[i] + bb[(size_t)i * nblk1 + blk];
    __syncthreads();

    const float wa0 = w_att[128], wa1 = w_att[129];
#pragma unroll
    for (int it = 0; it < EPB1 / 256; ++it) {
        int e = blk * EPB1 + it * 256 + tid;
        if (e < n_edge) {
            int s = esrc[e];
            int d = edst[e];
            float2 dd = *reinterpret_cast<const float2*>(&dist[2 * (size_t)e]);
            float sc = src_att[s] + dst_att[d] + dd.x * wa0 + dd.y * wa1;
            sc = (sc >= 0.f) ? sc : 0.2f * sc;
            float ew = __expf(sc);
            int pos = atomicAdd(&cur[((unsigned)d) >> 6], 1);
            meta1[pos] = make_float4(__int_as_float(s | ((d & 63) << 24)), ew, dd.x, dd.y);
        }
    }
}

// ---------------------------------------------------------------------------
// K_p2agg: fused fine-sort (in LDS) + softmax + aggregation.
//     One block per bucket of 64 dsts; 8 waves x 8 dsts; output written direct.
// ---------------------------------------------------------------------------
__global__ void __launch_bounds__(512)
p2agg_kernel(const float4* __restrict__ meta1, const int* __restrict__ binstart,
             const unsigned short* __restrict__ srcp,   // bf16 [n_src,128]
             const unsigned short* __restrict__ dstp,   // bf16 [n_dst,128]
             const float* __restrict__ w_embed,
             float* __restrict__ out, int n_dst)
{
    __shared__ float4 s_meta[CAP];        // 32 KB, fine-sorted bucket meta
    __shared__ int s_cnt[BDST];
    __shared__ int s_ofs[BDST + 1];
    __shared__ int s_cur[BDST];

    const int tid = threadIdx.x;
    const int b = blockIdx.x;
    const int bstart = binstart[b], bend = binstart[b + 1];
    const int bsize = bend - bstart;
    const int lane = tid & 63, wv = tid >> 6;   // 8 waves
    const int c0 = 2 * lane;

    const float2 wd0 = *reinterpret_cast<const float2*>(&w_embed[128 * D + c0]);
    const float2 wd1 = *reinterpret_cast<const float2*>(&w_embed[129 * D + c0]);

    if (tid < BDST) s_cnt[tid] = 0;
    __syncthreads();

    if (bsize <= CAP) {
        // pass A: fine counts (read only the packed word)
        for (int i = tid; i < bsize; i += 512) {
            int bits = __float_as_int(meta1[bstart + i].x);
            atomicAdd(&s_cnt[((unsigned)bits) >> 24], 1);
        }
        __syncthreads();
        // 64-bin exclusive scan in wave 0
        if (tid < BDST) {
            int v = s_cnt[tid];
            int x = v;
#pragma unroll
            for (int off = 1; off < 64; off <<= 1) {
                int y = __shfl_up(x, off);
                if (tid >= off) x += y;
            }
            s_ofs[tid] = x - v;
            s_cur[tid] = x - v;
            if (tid == 63) s_ofs[BDST] = x;
        }
        __syncthreads();
        // pass B: scatter full records into sorted LDS positions
        for (int i = tid; i < bsize; i += 512) {
            float4 m = meta1[bstart + i];
            int dlow = ((unsigned)__float_as_int(m.x)) >> 24;
            int pos = atomicAdd(&s_cur[dlow], 1);
            s_meta[pos] = m;
        }
        __syncthreads();

        // 8 waves x 8 dsts
#define EDGE_ACC(m)                                                               \
        {                                                                         \
            int bits_ = __float_as_int((m).x);                                    \
            unsigned int r_ = *reinterpret_cast<const unsigned int*>(             \
                &srcp[(size_t)(bits_ & 0xFFFFFF) * D + c0]);                      \
            acc0 += (m).y * bf16lo(r_);                                           \
            acc1 += (m).y * bf16hi(r_);                                           \
            sw   += (m).y;                                                        \
            swd0 += (m).y * (m).z;                                                \
            swd1 += (m).y * (m).w;                                                \
        }
#pragma unroll
        for (int k = 0; k < 8; ++k) {
            int dloc = k * 8 + wv;
            int gd = b * BDST + dloc;
            if (gd >= n_dst) continue;
            float2* op = reinterpret_cast<float2*>(&out[(size_t)gd * D + c0]);
            int o0 = s_ofs[dloc], o1 = s_ofs[dloc + 1];
            if (o0 == o1) { *op = make_float2(0.f, 0.f); continue; }

            float acc0 = 0.f, acc1 = 0.f, sw = 0.f, swd0 = 0.f, swd1 = 0.f;
            int j = o0;
            for (; j + 8 <= o1; j += 8) {
                float4 m0 = s_meta[j + 0];
                float4 m1 = s_meta[j + 1];
                float4 m2 = s_meta[j + 2];
                float4 m3 = s_meta[j + 3];
                float4 m4 = s_meta[j + 4];
                float4 m5 = s_meta[j + 5];
                float4 m6 = s_meta[j + 6];
                float4 m7 = s_meta[j + 7];
                EDGE_ACC(m0) EDGE_ACC(m1) EDGE_ACC(m2) EDGE_ACC(m3)
                EDGE_ACC(m4) EDGE_ACC(m5) EDGE_ACC(m6) EDGE_ACC(m7)
            }
            for (; j < o1; ++j) {
                float4 m0 = s_meta[j];
                EDGE_ACC(m0)
            }
            float inv = 1.f / sw;
            unsigned int rd = *reinterpret_cast<const unsigned int*>(&dstp[(size_t)gd * D + c0]);
            float ov0 = (acc0 + swd0 * wd0.x + swd1 * wd1.x) * inv + bf16lo(rd);
            float ov1 = (acc1 + swd0 * wd0.y + swd1 * wd1.y) * inv + bf16hi(rd);
            *op = make_float2(fmaxf(ov0, 0.f), fmaxf(ov1, 0.f));
        }
#undef EDGE_ACC
    } else {
        // robust slow path (never taken at these sizes): chunked scan
        float acc0[8], acc1[8], sw[8], s0[8], s1[8];
        for (int k = 0; k < 8; ++k) { acc0[k] = acc1[k] = sw[k] = s0[k] = s1[k] = 0.f; }
        for (int cs = bstart; cs < bend; cs += CAP) {
            int n = min(CAP, bend - cs);
            __syncthreads();
            for (int i = tid; i < n; i += 512) s_meta[i] = meta1[cs + i];
            __syncthreads();
            for (int k = 0; k < 8; ++k) {
                int dloc = k * 8 + wv;
                for (int i = 0; i < n; ++i) {
                    float4 m = s_meta[i];
                    int bits = __float_as_int(m.x);
                    if ((int)(((unsigned)bits) >> 24) == dloc) {
                        unsigned int r = *reinterpret_cast<const unsigned int*>(
                            &srcp[(size_t)(bits & 0xFFFFFF) * D + c0]);
                        acc0[k] += m.y * bf16lo(r);
                        acc1[k] += m.y * bf16hi(r);
                        sw[k] += m.y;
                        s0[k] += m.y * m.z;
                        s1[k] += m.y * m.w;
                    }
                }
            }
        }
        for (int k = 0; k < 8; ++k) {
            int dloc = k * 8 + wv;
            int gd = b * BDST + dloc;
            if (gd >= n_dst) continue;
            float2* op = reinterpret_cast<float2*>(&out[(size_t)gd * D + c0]);
            if (sw[k] == 0.f) { *op = make_float2(0.f, 0.f); continue; }
            float inv = 1.f / sw[k];
            unsigned int rd = *reinterpret_cast<const unsigned int*>(&dstp[(size_t)gd * D + c0]);
            float ov0 = (acc0[k] + s0[k] * wd0.x + s1[k] * wd1.x) * inv + bf16lo(rd);
            float ov1 = (acc1[k] + s0[k] * wd0.y + s1[k] * wd1.y) * inv + bf16hi(rd);
            *op = make_float2(fmaxf(ov0, 0.f), fmaxf(ov1, 0.f));
        }
    }
}

// ---------------------------------------------------------------------------
extern "C" void kernel_launch(void* const* d_in, const int* in_sizes, int n_in,
                              void* d_out, int out_size, void* d_ws, size_t ws_size,
                              hipStream_t stream)
{
    const float* src_feat = (const float*)d_in[0];   // [N_SRC,128]
    const int*   esrc     = (const int*)d_in[1];     // [E]
    const float* dst_feat = (const float*)d_in[2];   // [N_DST,128]
    const int*   edst     = (const int*)d_in[3];     // [E]
    const float* dist     = (const float*)d_in[4];   // [E,2]
    const float* w_att    = (const float*)d_in[5];   // [258]
    const float* w_embed  = (const float*)d_in[6];   // [258,128]

    const int n_src  = in_sizes[0] / D;
    const int n_edge = in_sizes[1];
    const int n_dst  = in_sizes[2] / D;

    const int nb1   = (n_dst + BDST - 1) / BDST;     // fine buckets (782)
    const int nblk1 = (n_edge + EPB1 - 1) / EPB1;    // pass-1 blocks (391)
    const size_t n1 = (size_t)nb1 * nblk1;

    // ---- workspace carve-up (256B-aligned) ----
    char* p = (char*)d_ws;
    auto carve = [&p](size_t bytes) {
        char* r = p;
        p += (bytes + 255) & ~size_t(255);
        return r;
    };
    unsigned short* src_projb = (unsigned short*)carve((size_t)n_src * D * 2);  // bf16
    unsigned short* dst_projb = (unsigned short*)carve((size_t)n_dst * D * 2);  // bf16
    float* src_att   = (float*)carve((size_t)n_src * 4);
    float* dst_att   = (float*)carve((size_t)n_dst * 4);
    int*   bb        = (int*)carve(n1 * 4);
    int*   bintot    = (int*)carve((size_t)nb1 * 4);
    int*   binstart  = (int*)carve((size_t)(nb1 + 1) * 4);
    unsigned short* w_frag = (unsigned short*)carve(2 * 4 * 8 * 64 * 8 * 2);  // 64 KB
    float4* meta1    = (float4*)carve((size_t)n_edge * 16);
    (void)ws_size;

    // K0: W -> bf16 fragment layout
    wconv_kernel<<<16, 256, 0, stream>>>(w_embed, w_frag);

    // K1: fused MFMA node projections
    const int nblk_src = (n_src + NPB - 1) / NPB;
    const int nblk_dst = (n_dst + NPB - 1) / NPB;
    proj_both_kernel<<<nblk_src + nblk_dst, 256, 0, stream>>>(
        src_feat, dst_feat, w_frag, w_att, n_src, n_dst, nblk_src,
        src_projb, dst_projb, src_att, dst_att);

    // K_h1: bucket histogram per pass1-block
    hist1_kernel<<<nblk1, 256, 0, stream>>>(edst, bb, n_edge, nblk1, nb1);

    // K_s1/K_s2: per-bin scan along blocks + bin-level scan
    scan_perbin_kernel<<<nb1, 64, 0, stream>>>(bb, bintot, nblk1);
    scan_bins_kernel<<<1, 1024, 0, stream>>>(bintot, binstart, nb1, n_edge);

    // K_p1: score/exp + bucket scatter (LDS cursors only)
    pass1_kernel<<<nblk1, 256, 0, stream>>>(esrc, edst, dist, src_att, dst_att,
                                            w_att, bb, binstart, meta1,
                                            n_edge, nblk1, nb1);

    // K_p2agg: fused fine-sort + softmax + aggregation
    p2agg_kernel<<<nb1, 512, 0, stream>>>(meta1, binstart, src_projb, dst_projb,
                                          w_embed, (float*)d_out, n_dst);
}